// Round 9
// baseline (184.792 us; speedup 1.0000x reference)
//
#include <hip/hip_runtime.h>
#include <hip/hip_bf16.h>
#include <cfloat>
#include <math.h>
#include <stdint.h>

#define N_TOK   32768
#define S_CODES 1024
#define C_DIM   256

typedef __attribute__((ext_vector_type(8))) short short8v;
typedef __attribute__((ext_vector_type(4))) float float4v;

// ---- workspace byte offsets ----
#define WS_HIST 0                       // 1024 int
#define WS_LOSS 4096                    // 1 float
#define WS_W2   4608                    // 1024 float
#define WS_WPK  16384                   // w_packed [1024 codes][8 kc][hi 64B | lo 64B] = 1 MB
#define WS_NEED ((size_t)(WS_WPK + 1048576))

__device__ __forceinline__ unsigned short f2bf(float f) {
    __hip_bfloat16 h = __float2bfloat16(f);
    return __builtin_bit_cast(unsigned short, h);
}
__device__ __forceinline__ float bf2f(unsigned short u) {
    return __bfloat162float(__builtin_bit_cast(__hip_bfloat16, u));
}

// ---- split w into packed hi/lo rows + squared norms; also zero hist/loss ----
__global__ void split_w(const float* __restrict__ w, unsigned short* __restrict__ wpack,
                        float* __restrict__ w2, int* __restrict__ hist,
                        float* __restrict__ lossp) {
    int c = blockIdx.x, l = threadIdx.x;       // 1024 blocks x 64 threads
    float4 v = ((const float4*)(w + (size_t)c * C_DIM))[l];   // k = l*4 .. +3
    float s = v.x*v.x + v.y*v.y + v.z*v.z + v.w*v.w;
    float vv[4] = {v.x, v.y, v.z, v.w};
    ushort4 h4, l4;
    unsigned short* hp = (unsigned short*)&h4;
    unsigned short* lp = (unsigned short*)&l4;
#pragma unroll
    for (int q = 0; q < 4; ++q) {
        hp[q] = f2bf(vv[q]);
        lp[q] = f2bf(vv[q] - bf2f(hp[q]));
    }
    size_t base = ((size_t)c * 8 + (l >> 3)) * 64;            // 64 shorts = 128 B per (c,kc)
    *(ushort4*)&wpack[base + (l & 7) * 4] = h4;               // hi half (bytes 0..63)
    *(ushort4*)&wpack[base + 32 + (l & 7) * 4] = l4;          // lo half (bytes 64..127)
#pragma unroll
    for (int off = 32; off > 0; off >>= 1) s += __shfl_down(s, off);
    if (l == 0) w2[c] = s;
    if (l == 32) hist[c] = 0;
    if (c == 0 && l == 33) *lossp = 0.f;
}

// ---- main: 64-token blocks (512 x 256 thr, 4 waves); wave w owns codes
//      [w*256,(w+1)*256). B loads DIRECT global->VGPR from L2-resident wpack via
//      INLINE-ASM global_load_dwordx4 (flat 64-bit VGPR address form — the r8
//      "s"-constraint base landed in a VGPR pair and failed to assemble) with
//      hand-counted vmcnt(8) and sched_barrier(0) fences: the compiler cannot
//      collapse this pipeline (r4/r5/r7 intrinsic prefetch collapsed, VGPR~104).
//      32 fully-static phases; ledger: 16 loads in flight, wait(8) retires the
//      consumed buffer, issue for phase g+2 after the MFMA cluster.
//      LDS holds only x hi/lo (64 KB) -> 2 blocks/CU, no barriers in K-loop. ----
__global__ void __launch_bounds__(256, 2)
vq_fused9(const float* __restrict__ x, const float* __restrict__ emb,
          const unsigned short* __restrict__ wpack, const float* __restrict__ w2g,
          float* __restrict__ out, int* __restrict__ hist, float* __restrict__ lossp) {
    __shared__ __align__(16) char smem[65536];
    unsigned short* xh = (unsigned short*)smem;               // [64 tok][256 k] bf16 hi
    unsigned short* xl = (unsigned short*)(smem + 32768);     // lo
    char* scr = smem;                                         // phase-3 overlay (xh dead)

    const int tid = threadIdx.x;
    const int l = tid & 63, wv = tid >> 6;    // 4 waves
    const int quad = l >> 4, lr = l & 15;
    const int t0 = blockIdx.x * 64;
    const int b = t0 >> 10, hw0 = t0 & 1023;
    const size_t xbase = ((size_t)b << 18) + hw0;
    const int wbase = wv * 256;               // this wave's code range
    const char* wpc = (const char*)wpack;

    // lane part of the B address (static per j): code = cb + j*16 + lr, chunk quad
    uint64_t voffj[4];
#pragma unroll
    for (int j = 0; j < 4; ++j)
        voffj[j] = (uint64_t)(j * 16384 + lr * 1024 + quad * 16);

    short8v bAh[4], bAl[4], bBh[4], bBl[4];   // two pinned B buffers
    short8v ah[4], al[4];
    const float4v zacc = {0.f, 0.f, 0.f, 0.f};
    float4v acc[4][4];
#pragma unroll
    for (int i = 0; i < 4; ++i)
#pragma unroll
        for (int j = 0; j < 4; ++j) acc[i][j] = zacc;

// flat 64-bit VGPR address form: global_load_dwordx4 vdst, v[a:a+1], off
#define LDJ(BH, BL, J, UB) do { \
        uint64_t a_ = (UB) + voffj[J]; \
        asm volatile("global_load_dwordx4 %0, %2, off\n\t" \
                     "global_load_dwordx4 %1, %2, off offset:64" \
                     : "=&v"(BH[J]), "=&v"(BL[J]) \
                     : "v"(a_) : "memory"); \
    } while (0)

#define ISSUE(BH, BL, CT, KC) do { \
        uint64_t ub_ = (uint64_t)(uintptr_t)wpc + \
                       (uint64_t)(((wbase + (CT) * 64) * 8 + (KC)) * 128); \
        LDJ(BH, BL, 0, ub_); LDJ(BH, BL, 1, ub_); \
        LDJ(BH, BL, 2, ub_); LDJ(BH, BL, 3, ub_); \
    } while (0)

    // prologue: phases 0,1 issued at kernel top — they land under phase 1 for free
    // (__syncthreads' vmcnt(0) drain retires them; the first two wait(8)s are no-ops)
    ISSUE(bAh, bAl, 0, 0);
    ISSUE(bBh, bBl, 0, 1);

    // w2 preload, statically indexed (rule 20) — keeps K-loop free of compiler vmem
    float w2r[16];
#pragma unroll
    for (int m = 0; m < 16; ++m)
        w2r[m] = w2g[wbase + (m >> 2) * 64 + (m & 3) * 16 + lr];

    // ---- phase 1: convert x (barrier-free, coalesced) ----
    float x2p = 0.f;
    {
        const int ctk = tid & 63, kq8 = tid >> 6;
#pragma unroll 1
        for (int c8 = 0; c8 < 8; ++c8) {
            int ch = kq8 * 8 + c8;
            const float* gp = x + xbase + (size_t)(ch * 8) * 1024 + ctk;
            float v8[8];
#pragma unroll
            for (int j2 = 0; j2 < 8; ++j2) v8[j2] = gp[(size_t)j2 * 1024];
            short8v hv, lv;
#pragma unroll
            for (int j2 = 0; j2 < 8; ++j2) {
                float v = v8[j2];
                unsigned short h = f2bf(v);
                float hf = bf2f(h);
                unsigned short lo = f2bf(v - hf);
                hv[j2] = (short)h; lv[j2] = (short)lo;
                x2p = fmaf(v, v, x2p);
            }
            int pos = ch ^ (ctk & 31);        // XOR swizzle, 16B chunks
            *(short8v*)&xh[ctk * 256 + pos * 8] = hv;
            *(short8v*)&xl[ctk * 256 + pos * 8] = lv;
        }
    }
    __syncthreads();                          // xh/xl ready; drains all vmem (ledger clean)

    // ---- A fragment offsets ----
    int aoffb[4], axor[4];
#pragma unroll
    for (int i = 0; i < 4; ++i) {
        int arow = i * 16 + lr;
        aoffb[i] = arow * 512;
        axor[i] = arow & 31;
    }

    float bval[16]; int bidx[16];
#pragma unroll
    for (int s2 = 0; s2 < 16; ++s2) { bval[s2] = FLT_MAX; bidx[s2] = 0; }

#define LOADA(KC) do { \
        _Pragma("unroll") \
        for (int i_ = 0; i_ < 4; ++i_) { \
            int pos_ = (((KC) * 4 + quad) ^ axor[i_]) * 16; \
            ah[i_] = *(const short8v*)(smem + aoffb[i_] + pos_); \
            al[i_] = *(const short8v*)(smem + 32768 + aoffb[i_] + pos_); \
        } \
    } while (0)

#define MMM(BH, BL) do { \
        __builtin_amdgcn_s_setprio(1); \
        _Pragma("unroll") \
        for (int i_ = 0; i_ < 4; ++i_) \
        _Pragma("unroll") \
        for (int j_ = 0; j_ < 4; ++j_) { \
            acc[i_][j_] = __builtin_amdgcn_mfma_f32_16x16x32_bf16(ah[i_], BH[j_], acc[i_][j_], 0, 0, 0); \
            acc[i_][j_] = __builtin_amdgcn_mfma_f32_16x16x32_bf16(ah[i_], BL[j_], acc[i_][j_], 0, 0, 0); \
            acc[i_][j_] = __builtin_amdgcn_mfma_f32_16x16x32_bf16(al[i_], BH[j_], acc[i_][j_], 0, 0, 0); \
        } \
        __builtin_amdgcn_s_setprio(0); \
    } while (0)

// phase G (static): ds-read A (issues before the wait -> latency overlaps it);
// counted wait retires buffer G; fenced MFMA cluster; issue loads for G+2.
#define STEP(G, CT, KC, NCT, NKC, DOI, WN) do { \
        LOADA(KC); \
        asm volatile("s_waitcnt vmcnt(" WN ")" ::: "memory"); \
        __builtin_amdgcn_sched_barrier(0); \
        if ((G) & 1) { MMM(bBh, bBl); } else { MMM(bAh, bAl); } \
        __builtin_amdgcn_sched_barrier(0); \
        if (DOI) { \
            if ((G) & 1) { ISSUE(bBh, bBl, NCT, NKC); } \
            else         { ISSUE(bAh, bAl, NCT, NKC); } \
        } \
    } while (0)

#define FOLD(CT) do { \
        _Pragma("unroll") \
        for (int j_ = 0; j_ < 4; ++j_) { \
            int code_ = wbase + (CT) * 64 + j_ * 16 + lr; \
            float w2c_ = w2r[(CT) * 4 + j_]; \
            _Pragma("unroll") \
            for (int i_ = 0; i_ < 4; ++i_) { \
                _Pragma("unroll") \
                for (int r_ = 0; r_ < 4; ++r_) { \
                    float sv_ = fmaf(-2.f, acc[i_][j_][r_], w2c_); \
                    int sl_ = i_ * 4 + r_; \
                    if (sv_ < bval[sl_]) { bval[sl_] = sv_; bidx[sl_] = code_; } \
                } \
                acc[i_][j_] = zacc; \
            } \
        } \
    } while (0)

    // ---- phase 2: 32 static phases (4 ct x 8 kc) ----
    STEP( 0,0,0, 0,2, 1,"8"); STEP( 1,0,1, 0,3, 1,"8");
    STEP( 2,0,2, 0,4, 1,"8"); STEP( 3,0,3, 0,5, 1,"8");
    STEP( 4,0,4, 0,6, 1,"8"); STEP( 5,0,5, 0,7, 1,"8");
    STEP( 6,0,6, 1,0, 1,"8"); STEP( 7,0,7, 1,1, 1,"8");
    FOLD(0);
    STEP( 8,1,0, 1,2, 1,"8"); STEP( 9,1,1, 1,3, 1,"8");
    STEP(10,1,2, 1,4, 1,"8"); STEP(11,1,3, 1,5, 1,"8");
    STEP(12,1,4, 1,6, 1,"8"); STEP(13,1,5, 1,7, 1,"8");
    STEP(14,1,6, 2,0, 1,"8"); STEP(15,1,7, 2,1, 1,"8");
    FOLD(1);
    STEP(16,2,0, 2,2, 1,"8"); STEP(17,2,1, 2,3, 1,"8");
    STEP(18,2,2, 2,4, 1,"8"); STEP(19,2,3, 2,5, 1,"8");
    STEP(20,2,4, 2,6, 1,"8"); STEP(21,2,5, 2,7, 1,"8");
    STEP(22,2,6, 3,0, 1,"8"); STEP(23,2,7, 3,1, 1,"8");
    FOLD(2);
    STEP(24,3,0, 3,2, 1,"8"); STEP(25,3,1, 3,3, 1,"8");
    STEP(26,3,2, 3,4, 1,"8"); STEP(27,3,3, 3,5, 1,"8");
    STEP(28,3,4, 3,6, 1,"8"); STEP(29,3,5, 3,7, 1,"8");
    STEP(30,3,6, 0,0, 0,"8"); STEP(31,3,7, 0,0, 0,"0");
    FOLD(3);

#undef STEP
#undef FOLD
#undef MMM
#undef LOADA
#undef ISSUE
#undef LDJ

    // ---- phase 3: argmin reduce, histogram, loss, gather/write ----
    __syncthreads();                          // xh dead -> scr overlay
    float* bestv = (float*)scr;               // [4][64]
    int*   besti = (int*)(scr + 1024);        // [4][64]
    int*   idx_sh = (int*)(scr + 2048);       // [64]
    float* x2sh  = (float*)(scr + 2304);      // [4][64]
    x2sh[tid] = x2p;                          // tid = kq8*64 + ctk
#pragma unroll
    for (int slot = 0; slot < 16; ++slot) {
        float bv = bval[slot]; int bi = bidx[slot];
#pragma unroll
        for (int off = 1; off < 16; off <<= 1) {
            float ov = __shfl_xor(bv, off);
            int   oi = __shfl_xor(bi, off);
            if (ov < bv || (ov == bv && oi < bi)) { bv = ov; bi = oi; }
        }
        if (lr == 0) {
            int tloc = (slot >> 2) * 16 + quad * 4 + (slot & 3);   // token 0..63
            bestv[wv * 64 + tloc] = bv; besti[wv * 64 + tloc] = bi;
        }
    }
    __syncthreads();
    if (tid < 64) {
        float bv = bestv[tid]; int bi = besti[tid];
#pragma unroll
        for (int w = 1; w < 4; ++w) {
            float ov = bestv[w * 64 + tid];
            int   oi = besti[w * 64 + tid];
            if (ov < bv || (ov == bv && oi < bi)) { bv = ov; bi = oi; }
        }
        idx_sh[tid] = bi;
        atomicAdd(&hist[bi], 1);
        float x2tok = x2sh[tid] + x2sh[64 + tid] + x2sh[128 + tid] + x2sh[192 + tid];
        float lsum = bv + x2tok;              // |q-x|^2 = (w2 - 2 q.x) + x^2
#pragma unroll
        for (int off = 32; off > 0; off >>= 1) lsum += __shfl_down(lsum, off);
        if (tid == 0) atomicAdd(lossp, lsum);
    }
    __syncthreads();
    {
        int t = tid & 63, cg = tid >> 6;      // 4 dim-groups of 64
        int id = idx_sh[t];
        const float* erow = emb + (size_t)id * C_DIM;
        float* ob = out + xbase + t;
#pragma unroll
        for (int cb2 = 0; cb2 < 16; ++cb2) {
            int c4 = cb2 * 16 + cg * 4;
            float4 q4 = *(const float4*)&erow[c4];
            ob[(size_t)(c4 + 0) * 1024] = q4.x;
            ob[(size_t)(c4 + 1) * 1024] = q4.y;
            ob[(size_t)(c4 + 2) * 1024] = q4.z;
            ob[(size_t)(c4 + 3) * 1024] = q4.w;
        }
    }
}

__global__ void finalize_kernel(const int* __restrict__ hist, const float* __restrict__ lossp,
                                float* __restrict__ out) {
    __shared__ float red[16];
    int tid = threadIdx.x;                  // 1024 threads
    float p = (float)hist[tid] * (1.f / 32768.f);
    float term = p * logf(p + 1e-6f);
#pragma unroll
    for (int off = 32; off > 0; off >>= 1) term += __shfl_down(term, off);
    if ((tid & 63) == 0) red[tid >> 6] = term;
    __syncthreads();
    if (tid == 0) {
        float s = 0.f;
#pragma unroll
        for (int i = 0; i < 16; ++i) s += red[i];
        out[8388608] = 0.25f * lossp[0] * (1.f / 8388608.f);   // quant_loss
        out[8388609] = expf(-s);                               // perplexity
    }
}

// ---- fallback path (round-1 kernel, known-correct) used only if ws too small ----
__global__ void w2_kernel(const float* __restrict__ w, float* __restrict__ w2) {
    int code = blockIdx.x * blockDim.x + threadIdx.x;
    const float4* r = (const float4*)(w + (size_t)code * C_DIM);
    float s = 0.f;
#pragma unroll 8
    for (int i = 0; i < C_DIM / 4; ++i) {
        float4 v = r[i];
        s += v.x * v.x + v.y * v.y + v.z * v.z + v.w * v.w;
    }
    w2[code] = s;
}

__launch_bounds__(256, 2)
__global__ void vq_main(const float* __restrict__ x, const float* __restrict__ emb,
                        float* __restrict__ out, int* __restrict__ hist,
                        float* __restrict__ lossp, const float* __restrict__ w2) {
    __shared__ float w_lds[8 * S_CODES];
    __shared__ float x_lds[C_DIM * 32];
    const int tid = threadIdx.x;
    const int l = tid & 63, wv = tid >> 6;
    const int t0 = blockIdx.x * 32;
    const int b = t0 >> 10, hw0 = t0 & 1023;
    const float* xbase = x + ((size_t)b * C_DIM << 10) + hw0;
    {
        int rl = tid & 7, r0 = tid >> 3;
        for (int rep = 0; rep < 8; ++rep) {
            int c = rep * 32 + r0;
            float4 v = *(const float4*)(xbase + ((size_t)c << 10) + rl * 4);
            *(float4*)&x_lds[c * 32 + rl * 4] = v;
        }
    }
    float4 pre[8];
#pragma unroll
    for (int m = 0; m < 8; ++m) {
        int fid = m * 256 + tid;
        int code = fid >> 1, kq = fid & 1;
        pre[m] = *(const float4*)(emb + (size_t)code * C_DIM + kq * 4);
    }
    float acc[8][16];
#pragma unroll
    for (int t = 0; t < 8; ++t)
#pragma unroll
        for (int j = 0; j < 16; ++j) acc[t][j] = 0.f;
    __syncthreads();
    for (int chunk = 0; chunk < 32; ++chunk) {
#pragma unroll
        for (int m = 0; m < 8; ++m) {
            int fid = m * 256 + tid;
            int code = fid >> 1, kq = fid & 1;
            float4 v = pre[m];
            w_lds[(kq * 4 + 0) * S_CODES + code] = v.x;
            w_lds[(kq * 4 + 1) * S_CODES + code] = v.y;
            w_lds[(kq * 4 + 2) * S_CODES + code] = v.z;
            w_lds[(kq * 4 + 3) * S_CODES + code] = v.w;
        }
        if (chunk + 1 < 32) {
            int k0n = (chunk + 1) * 8;
#pragma unroll
            for (int m = 0; m < 8; ++m) {
                int fid = m * 256 + tid;
                int code = fid >> 1, kq = fid & 1;
                pre[m] = *(const float4*)(emb + (size_t)code * C_DIM + k0n + kq * 4);
            }
        }
        __syncthreads();
        int k0 = chunk * 8;
#pragma unroll
        for (int kk = 0; kk < 8; ++kk) {
            int k = k0 + kk;
            float4 wq0 = *(const float4*)&w_lds[kk * S_CODES +   0 + l * 4];
            float4 wq1 = *(const float4*)&w_lds[kk * S_CODES + 256 + l * 4];
            float4 wq2 = *(const float4*)&w_lds[kk * S_CODES + 512 + l * 4];
            float4 wq3 = *(const float4*)&w_lds[kk * S_CODES + 768 + l * 4];
            float4 xa = *(const float4*)&x_lds[k * 32 + wv * 8];
            float4 xb = *(const float4*)&x_lds[k * 32 + wv * 8 + 4];
            float xs[8] = {xa.x, xa.y, xa.z, xa.w, xb.x, xb.y, xb.z, xb.w};
            float wvv[16] = {wq0.x, wq0.y, wq0.z, wq0.w, wq1.x, wq1.y, wq1.z, wq1.w,
                             wq2.x, wq2.y, wq2.z, wq2.w, wq3.x, wq3.y, wq3.z, wq3.w};
#pragma unroll
            for (int t = 0; t < 8; ++t) {
                float xv = xs[t];
#pragma unroll
                for (int j = 0; j < 16; ++j) acc[t][j] = fmaf(xv, wvv[j], acc[t][j]);
            }
        }
        __syncthreads();
    }
    float w2v[16];
#pragma unroll
    for (int m = 0; m < 4; ++m) {
        float4 v = *(const float4*)&w2[m * 256 + l * 4];
        w2v[m*4+0] = v.x; w2v[m*4+1] = v.y; w2v[m*4+2] = v.z; w2v[m*4+3] = v.w;
    }
    int* idx_sh = (int*)w_lds;
    float* red = (float*)(w_lds + 64);
#pragma unroll
    for (int t = 0; t < 8; ++t) {
        float bv = FLT_MAX; int bi = 0;
#pragma unroll
        for (int m = 0; m < 4; ++m)
#pragma unroll
            for (int j = 0; j < 4; ++j) {
                float s = w2v[m*4+j] - 2.f * acc[t][m*4+j];
                int c = m * 256 + l * 4 + j;
                if (s < bv) { bv = s; bi = c; }
            }
#pragma unroll
        for (int off = 32; off > 0; off >>= 1) {
            float ov = __shfl_xor(bv, off);
            int oi = __shfl_xor(bi, off);
            if (ov < bv || (ov == bv && oi < bi)) { bv = ov; bi = oi; }
        }
        if (l == 0) idx_sh[wv * 8 + t] = bi;
    }
    __syncthreads();
    if (tid < 32) atomicAdd(&hist[idx_sh[tid]], 1);
    float lsum = 0.f;
    for (int e = tid; e < C_DIM * 32; e += 256) {
        int t = e & 31, c = e >> 5;
        int id = idx_sh[t];
        float q = emb[(size_t)id * C_DIM + c];
        float xv = x_lds[c * 32 + t];
        float d = q - xv;
        lsum += d * d;
        out[((size_t)(b * C_DIM + c) << 10) + hw0 + t] = q;
    }
#pragma unroll
    for (int off = 32; off > 0; off >>= 1) lsum += __shfl_down(lsum, off);
    if (l == 0) red[wv] = lsum;
    __syncthreads();
    if (tid == 0) atomicAdd(lossp, red[0] + red[1] + red[2] + red[3]);
}

extern "C" void kernel_launch(void* const* d_in, const int* in_sizes, int n_in,
                              void* d_out, int out_size, void* d_ws, size_t ws_size,
                              hipStream_t stream) {
    const float* x   = (const float*)d_in[0];
    const float* emb = (const float*)d_in[1];
    float* out = (float*)d_out;
    char* ws = (char*)d_ws;
    int*   hist  = (int*)(ws + WS_HIST);
    float* lossp = (float*)(ws + WS_LOSS);
    float* w2    = (float*)(ws + WS_W2);

    if (ws_size >= WS_NEED) {
        unsigned short* wpack = (unsigned short*)(ws + WS_WPK);
        split_w<<<1024, 64, 0, stream>>>(emb, wpack, w2, hist, lossp);
        vq_fused9<<<512, 256, 0, stream>>>(x, emb, wpack, w2, out, hist, lossp);
    } else {
        hipMemsetAsync(d_ws, 0, 4608, stream);
        w2_kernel<<<4, 256, 0, stream>>>(emb, w2);
        vq_main<<<1024, 256, 0, stream>>>(x, emb, out, hist, lossp, w2);
    }
    finalize_kernel<<<1, 1024, 0, stream>>>(hist, lossp, out);
}

// Round 10
// 153.910 us; speedup vs baseline: 1.2006x; 1.2006x over previous
//
#include <hip/hip_runtime.h>
#include <hip/hip_bf16.h>
#include <cfloat>
#include <math.h>

#define N_TOK   32768
#define S_CODES 1024
#define C_DIM   256

typedef __attribute__((ext_vector_type(8))) short short8v;
typedef __attribute__((ext_vector_type(4))) float float4v;

// ---- workspace byte offsets ----
#define WS_HIST 0                       // 1024 int
#define WS_LOSS 4096                    // 1 float
#define WS_W2   4608                    // 1024 float (ends 8704)
#define WS_CNT  12288                   // 1 int completion counter
#define WS_WPK  16384                   // w_packed [1024 codes][8 kc][hi 64B | lo 64B] = 1 MB
#define WS_NEED ((size_t)(WS_WPK + 1048576))

__device__ __forceinline__ unsigned short f2bf(float f) {
    __hip_bfloat16 h = __float2bfloat16(f);
    return __builtin_bit_cast(unsigned short, h);
}
__device__ __forceinline__ float bf2f(unsigned short u) {
    return __bfloat162float(__builtin_bit_cast(__hip_bfloat16, u));
}
__device__ __forceinline__ void gload16(const void* g, void* l) {
    __builtin_amdgcn_global_load_lds((const __attribute__((address_space(1))) void*)g,
                                     (__attribute__((address_space(3))) void*)l, 16, 0, 0);
}

// ---- split w into packed hi/lo rows + squared norms; zero hist/loss/counter ----
__global__ void split_w(const float* __restrict__ w, unsigned short* __restrict__ wpack,
                        float* __restrict__ w2, int* __restrict__ hist,
                        float* __restrict__ lossp, int* __restrict__ cntp) {
    int c = blockIdx.x, l = threadIdx.x;       // 1024 blocks x 64 threads
    float4 v = ((const float4*)(w + (size_t)c * C_DIM))[l];   // k = l*4 .. +3
    float s = v.x*v.x + v.y*v.y + v.z*v.z + v.w*v.w;
    float vv[4] = {v.x, v.y, v.z, v.w};
    ushort4 h4, l4;
    unsigned short* hp = (unsigned short*)&h4;
    unsigned short* lp = (unsigned short*)&l4;
#pragma unroll
    for (int q = 0; q < 4; ++q) {
        hp[q] = f2bf(vv[q]);
        lp[q] = f2bf(vv[q] - bf2f(hp[q]));
    }
    size_t base = ((size_t)c * 8 + (l >> 3)) * 64;            // 64 shorts = 128 B per (c,kc)
    *(ushort4*)&wpack[base + (l & 7) * 4] = h4;               // hi half (bytes 0..63)
    *(ushort4*)&wpack[base + 32 + (l & 7) * 4] = l4;          // lo half (bytes 64..127)
#pragma unroll
    for (int off = 32; off > 0; off >>= 1) s += __shfl_down(s, off);
    if (l == 0) w2[c] = s;
    if (l == 32) hist[c] = 0;
    if (c == 0 && l == 33) *lossp = 0.f;
    if (c == 0 && l == 34) *cntp = 0;
}

// ---- main (r5's verified 77us kernel + fused last-block finalize).
//      128-token blocks, 8 waves (th = wv&1 token-half, cq = wv>>1 code-quarter).
//      x converted once, DIRECTLY from coalesced global reads into full-K LDS
//      hi/lo (128 KB); first two W tiles' DMA issued BEFORE phase 1. W staged via
//      global_load_lds 16 KB tiles, double-buffered, counted vmcnt(2).
//      The LAST block to finish (device-scope counter) computes loss/perplexity
//      with finalize_kernel's EXACT reduction order -> bit-identical outputs,
//      one fewer dispatch per iteration. ----
__global__ void __launch_bounds__(512, 2)
vq_fused6(const float* __restrict__ x, const float* __restrict__ emb,
          const unsigned short* __restrict__ wpack, const float* __restrict__ w2g,
          float* __restrict__ out, int* __restrict__ hist, float* __restrict__ lossp,
          int* __restrict__ cntp) {
    __shared__ __align__(16) char smem[163840];
    // layout: xh [128 tok][256 k] bf16 (64 KB) | xl (64 KB) | W dbuf 2x16 KB
    unsigned short* xh = (unsigned short*)smem;
    unsigned short* xl = (unsigned short*)(smem + 65536);
    char* wbuf = smem + 131072;               // two 16 KB tile buffers
    char* scr  = smem + 131072;               // phase-3 scratch overlay (32 KB)

    const int tid = threadIdx.x;
    const int l = tid & 63, wv = tid >> 6;
    const int quad = l >> 4, lr = l & 15;
    const int th = wv & 1, cq = wv >> 1;      // token half / code quarter
    const int t0 = blockIdx.x * 128;
    const int b = t0 >> 10, hw0 = t0 & 1023;
    const size_t xbase = ((size_t)b << 18) + hw0;

    const int drq = l >> 3;                   // DMA: row within 8-row group
    const int dch = (l & 7) ^ (drq & 7);      // source chunk (un-swizzle)
    const char* wpc = (const char*)wpack;

    // stage 16 KB tile g (strip g>>3, kc g&7) into wbuf[g&1]; 8 waves x 2 KB
    auto STAGE = [&](int g) {
        int sp = g >> 3, kcp = g & 7;
        char* dst = wbuf + (g & 1) * 16384 + wv * 2048;
#pragma unroll
        for (int u = 0; u < 2; ++u) {
            int code = sp * 128 + wv * 16 + u * 8 + drq;
            size_t src = ((size_t)code * 8 + kcp) * 128 + (size_t)dch * 16;
            gload16(wpc + src, dst + u * 1024);
        }
    };

    // W tiles 0,1 DMA in flight during all of phase 1
    STAGE(0);
    STAGE(1);

    // ---- phase 1: convert x, barrier-free (coalesced scalar loads) ----
    float x2p = 0.f;                          // partial |x|^2: token ct, k-quarter kq
    {
        const int ct = tid & 127, kq = tid >> 7;
        const float* gp0 = x + xbase + (size_t)(kq * 8) * 1024 + ct;
#pragma unroll 2
        for (int kc = 0; kc < 8; ++kc) {
            const float* gp = gp0 + (size_t)(kc * 32) * 1024;
            float v8[8];
#pragma unroll
            for (int j2 = 0; j2 < 8; ++j2) v8[j2] = gp[(size_t)j2 * 1024];
            short8v hv, lv;
#pragma unroll
            for (int j2 = 0; j2 < 8; ++j2) {
                float v = v8[j2];
                unsigned short h = f2bf(v);
                float hf = bf2f(h);
                unsigned short lo = f2bf(v - hf);
                hv[j2] = (short)h; lv[j2] = (short)lo;
                x2p = fmaf(v, v, x2p);
            }
            int pos = (kc * 4 + kq) ^ (ct & 31);          // XOR swizzle, 16B chunks
            *(short8v*)&xh[ct * 256 + pos * 8] = hv;
            *(short8v*)&xl[ct * 256 + pos * 8] = lv;
        }
    }
    __syncthreads();   // xh/xl ready; full drain also retires tile-0/1 DMA

    // ---- precomputed fragment offsets ----
    int aoffb[4], axor[4];
#pragma unroll
    for (int i = 0; i < 4; ++i) {
        int arow = th * 64 + i * 16 + lr;     // token row 0..127
        aoffb[i] = arow * 512;                // bytes (row = 256 shorts)
        axor[i] = arow & 31;
    }
    int boff_h[2], boff_l[2];
#pragma unroll
    for (int j = 0; j < 2; ++j) {
        int brow = cq * 32 + j * 16 + lr;     // row in 128-code tile, 128 B rows
        boff_h[j] = brow * 128 + ((quad ^ (brow & 7)) * 16);
        boff_l[j] = brow * 128 + (((4 + quad) ^ (brow & 7)) * 16);
    }

    float bval[16]; int bidx[16];
#pragma unroll
    for (int s2 = 0; s2 < 16; ++s2) { bval[s2] = FLT_MAX; bidx[s2] = 0; }
    const float4v zacc = {0.f, 0.f, 0.f, 0.f};
    float4v acc[4][2];
#pragma unroll
    for (int i = 0; i < 4; ++i)
#pragma unroll
        for (int j = 0; j < 2; ++j) acc[i][j] = zacc;

    struct Frags { short8v ah[4], al[4], bh[2], bl[2]; };
    Frags f0, f1;

    // read the 12 fragments for step g into f (A from immutable xh/xl, B from wbuf)
    auto READF = [&](Frags& f, int g) {
        const int kc = g & 7;
        const char* bufp = wbuf + (g & 1) * 16384;
#pragma unroll
        for (int i = 0; i < 4; ++i) {
            int pos = ((kc * 4 + quad) ^ axor[i]) * 16;
            f.ah[i] = *(const short8v*)(smem + aoffb[i] + pos);
            f.al[i] = *(const short8v*)(smem + 65536 + aoffb[i] + pos);
        }
#pragma unroll
        for (int j = 0; j < 2; ++j) {
            f.bh[j] = *(const short8v*)(bufp + boff_h[j]);
            f.bl[j] = *(const short8v*)(bufp + boff_l[j]);
        }
    };

    auto COMPUTE = [&](const Frags& f) {
        __builtin_amdgcn_s_setprio(1);
#pragma unroll
        for (int i = 0; i < 4; ++i)
#pragma unroll
            for (int j = 0; j < 2; ++j) {
                acc[i][j] = __builtin_amdgcn_mfma_f32_16x16x32_bf16(f.ah[i], f.bh[j], acc[i][j], 0, 0, 0);
                acc[i][j] = __builtin_amdgcn_mfma_f32_16x16x32_bf16(f.ah[i], f.bl[j], acc[i][j], 0, 0, 0);
                acc[i][j] = __builtin_amdgcn_mfma_f32_16x16x32_bf16(f.al[i], f.bh[j], acc[i][j], 0, 0, 0);
            }
        __builtin_amdgcn_s_setprio(0);
    };

    auto FOLD = [&](int s) {
#pragma unroll
        for (int j = 0; j < 2; ++j) {
            int code = s * 128 + cq * 32 + j * 16 + lr;
            float w2c = w2g[code];
#pragma unroll
            for (int i = 0; i < 4; ++i) {
#pragma unroll
                for (int rr = 0; rr < 4; ++rr) {
                    float sv = fmaf(-2.f, acc[i][j][rr], w2c);
                    int slot = i * 4 + rr;
                    if (sv < bval[slot]) { bval[slot] = sv; bidx[slot] = code; }
                }
                acc[i][j] = zacc;
            }
        }
    };

#define SBAR0() __builtin_amdgcn_sched_barrier(0)

    // ---- phase 2: 64 steps, frag-pipelined (read g+1 while computing g) ----
    READF(f0, 0);

#pragma unroll 1
    for (int t = 0; t < 31; ++t) {
        const int g = 2 * t;
        asm volatile("s_barrier" ::: "memory");        // frags g read by all -> buf[g&1] free
        STAGE(g + 2);
        asm volatile("s_waitcnt vmcnt(2)\n\ts_barrier" ::: "memory");  // tile g+1 ready
        READF(f1, g + 1);
        SBAR0();
        COMPUTE(f0);
        SBAR0();
        asm volatile("s_barrier" ::: "memory");
        STAGE(g + 3);
        asm volatile("s_waitcnt vmcnt(2)\n\ts_barrier" ::: "memory");
        READF(f0, g + 2);
        SBAR0();
        COMPUTE(f1);
        SBAR0();
        if ((t & 3) == 3) FOLD((2 * t + 1) >> 3);      // strip fold at g = 7,15,..,55
    }
    asm volatile("s_barrier" ::: "memory");            // frags 62 read -> safe
    asm volatile("s_waitcnt vmcnt(0)\n\ts_barrier" ::: "memory");      // tile 63 ready
    READF(f1, 63);
    SBAR0();
    COMPUTE(f0);
    SBAR0();
    COMPUTE(f1);
    FOLD(7);

    // ---- phase 3: x2 reduce, argmin reduce, histogram, loss, gather/write ----
    __syncthreads();                          // all DMA + reads done; scr free
    float* bestv = (float*)scr;               // [8][64]
    int*   besti = (int*)(scr + 2048);        // [8][64]
    int*   idx_sh = (int*)(scr + 4096);       // [128]
    float* x2sh  = (float*)(scr + 8192);      // [4][128]
    float* redf  = (float*)(scr + 12288);     // [16] finalize partials
    int*   lastf = (int*)(scr + 12352);       // last-block flag
    x2sh[tid] = x2p;                          // tid = kq*128 + ct
#pragma unroll
    for (int slot = 0; slot < 16; ++slot) {
        float bv = bval[slot]; int bi = bidx[slot];
#pragma unroll
        for (int off = 1; off < 16; off <<= 1) {
            float ov = __shfl_xor(bv, off);
            int   oi = __shfl_xor(bi, off);
            if (ov < bv || (ov == bv && oi < bi)) { bv = ov; bi = oi; }
        }
        if (lr == 0) {
            int tloc = (slot >> 2) * 16 + quad * 4 + (slot & 3);   // 0..63 within half
            bestv[wv * 64 + tloc] = bv; besti[wv * 64 + tloc] = bi;
        }
    }
    __syncthreads();
    if (tid < 128) {
        float x2tok = x2sh[tid] + x2sh[128 + tid] + x2sh[256 + tid] + x2sh[384 + tid];
        int th2 = tid >> 6, tl = tid & 63;    // waves with th==th2: {th2, th2+2, th2+4, th2+6}
        float bv = bestv[th2 * 64 + tl]; int bi = besti[th2 * 64 + tl];
#pragma unroll
        for (int w = 1; w < 4; ++w) {
            float ov = bestv[(w * 2 + th2) * 64 + tl];
            int   oi = besti[(w * 2 + th2) * 64 + tl];
            if (ov < bv || (ov == bv && oi < bi)) { bv = ov; bi = oi; }
        }
        idx_sh[tid] = bi;
        atomicAdd(&hist[bi], 1);
        float lsum = bv + x2tok;              // |q-x|^2 = (w2 - 2 q.x) + x^2
#pragma unroll
        for (int off = 32; off > 0; off >>= 1) lsum += __shfl_down(lsum, off);
        if ((tid & 63) == 0) atomicAdd(lossp, lsum);
    }
    __syncthreads();                          // hist/loss atomics complete (vmcnt drain)
    {
        int t = tid & 127, cg = tid >> 7;
        int id = idx_sh[t];
        const float* erow = emb + (size_t)id * C_DIM;
        float* ob = out + xbase + t;
#pragma unroll
        for (int cb = 0; cb < 16; ++cb) {
            int c4 = cb * 16 + cg * 4;
            float4 q4 = *(const float4*)&erow[c4];
            ob[(size_t)(c4 + 0) * 1024] = q4.x;
            ob[(size_t)(c4 + 1) * 1024] = q4.y;
            ob[(size_t)(c4 + 2) * 1024] = q4.z;
            ob[(size_t)(c4 + 3) * 1024] = q4.w;
        }
    }

    // ---- fused finalize: last block computes loss/perplexity (exact order) ----
    __syncthreads();
    if (tid == 0) {
        __threadfence();                      // hist/loss visible device-wide
        int old = atomicAdd(cntp, 1);
        *lastf = (old == (int)gridDim.x - 1);
    }
    __syncthreads();
    if (*lastf) {
        // emulate finalize_kernel exactly: 16 virtual waves, same shuffle tree,
        // same sequential 16-term sum. hist/lossp fetched via device-scope atomics
        // (cross-XCD L2s are not coherent for plain loads).
#pragma unroll
        for (int vw = 0; vw < 2; ++vw) {
            int W = wv * 2 + vw;              // virtual wave 0..15
            int code = W * 64 + l;
            float p = (float)atomicAdd(&hist[code], 0) * (1.f / 32768.f);
            float term = p * logf(p + 1e-6f);
#pragma unroll
            for (int off = 32; off > 0; off >>= 1) term += __shfl_down(term, off);
            if (l == 0) redf[W] = term;
        }
        __syncthreads();
        if (tid == 0) {
            float s = 0.f;
#pragma unroll
            for (int i = 0; i < 16; ++i) s += redf[i];
            float lv = atomicAdd(lossp, 0.f);
            out[8388608] = 0.25f * lv * (1.f / 8388608.f);   // quant_loss
            out[8388609] = expf(-s);                         // perplexity
        }
    }
#undef SBAR0
}

__global__ void finalize_kernel(const int* __restrict__ hist, const float* __restrict__ lossp,
                                float* __restrict__ out) {
    __shared__ float red[16];
    int tid = threadIdx.x;                  // 1024 threads
    float p = (float)hist[tid] * (1.f / 32768.f);
    float term = p * logf(p + 1e-6f);
#pragma unroll
    for (int off = 32; off > 0; off >>= 1) term += __shfl_down(term, off);
    if ((tid & 63) == 0) red[tid >> 6] = term;
    __syncthreads();
    if (tid == 0) {
        float s = 0.f;
#pragma unroll
        for (int i = 0; i < 16; ++i) s += red[i];
        out[8388608] = 0.25f * lossp[0] * (1.f / 8388608.f);   // quant_loss
        out[8388609] = expf(-s);                               // perplexity
    }
}

// ---- fallback path (round-1 kernel, known-correct) used only if ws too small ----
__global__ void w2_kernel(const float* __restrict__ w, float* __restrict__ w2) {
    int code = blockIdx.x * blockDim.x + threadIdx.x;
    const float4* r = (const float4*)(w + (size_t)code * C_DIM);
    float s = 0.f;
#pragma unroll 8
    for (int i = 0; i < C_DIM / 4; ++i) {
        float4 v = r[i];
        s += v.x * v.x + v.y * v.y + v.z * v.z + v.w * v.w;
    }
    w2[code] = s;
}

__launch_bounds__(256, 2)
__global__ void vq_main(const float* __restrict__ x, const float* __restrict__ emb,
                        float* __restrict__ out, int* __restrict__ hist,
                        float* __restrict__ lossp, const float* __restrict__ w2) {
    __shared__ float w_lds[8 * S_CODES];
    __shared__ float x_lds[C_DIM * 32];
    const int tid = threadIdx.x;
    const int l = tid & 63, wv = tid >> 6;
    const int t0 = blockIdx.x * 32;
    const int b = t0 >> 10, hw0 = t0 & 1023;
    const float* xbase = x + ((size_t)b * C_DIM << 10) + hw0;
    {
        int rl = tid & 7, r0 = tid >> 3;
        for (int rep = 0; rep < 8; ++rep) {
            int c = rep * 32 + r0;
            float4 v = *(const float4*)(xbase + ((size_t)c << 10) + rl * 4);
            *(float4*)&x_lds[c * 32 + rl * 4] = v;
        }
    }
    float4 pre[8];
#pragma unroll
    for (int m = 0; m < 8; ++m) {
        int fid = m * 256 + tid;
        int code = fid >> 1, kq = fid & 1;
        pre[m] = *(const float4*)(emb + (size_t)code * C_DIM + kq * 4);
    }
    float acc[8][16];
#pragma unroll
    for (int t = 0; t < 8; ++t)
#pragma unroll
        for (int j = 0; j < 16; ++j) acc[t][j] = 0.f;
    __syncthreads();
    for (int chunk = 0; chunk < 32; ++chunk) {
#pragma unroll
        for (int m = 0; m < 8; ++m) {
            int fid = m * 256 + tid;
            int code = fid >> 1, kq = fid & 1;
            float4 v = pre[m];
            w_lds[(kq * 4 + 0) * S_CODES + code] = v.x;
            w_lds[(kq * 4 + 1) * S_CODES + code] = v.y;
            w_lds[(kq * 4 + 2) * S_CODES + code] = v.z;
            w_lds[(kq * 4 + 3) * S_CODES + code] = v.w;
        }
        if (chunk + 1 < 32) {
            int k0n = (chunk + 1) * 8;
#pragma unroll
            for (int m = 0; m < 8; ++m) {
                int fid = m * 256 + tid;
                int code = fid >> 1, kq = fid & 1;
                pre[m] = *(const float4*)(emb + (size_t)code * C_DIM + k0n + kq * 4);
            }
        }
        __syncthreads();
        int k0 = chunk * 8;
#pragma unroll
        for (int kk = 0; kk < 8; ++kk) {
            int k = k0 + kk;
            float4 wq0 = *(const float4*)&w_lds[kk * S_CODES +   0 + l * 4];
            float4 wq1 = *(const float4*)&w_lds[kk * S_CODES + 256 + l * 4];
            float4 wq2 = *(const float4*)&w_lds[kk * S_CODES + 512 + l * 4];
            float4 wq3 = *(const float4*)&w_lds[kk * S_CODES + 768 + l * 4];
            float4 xa = *(const float4*)&x_lds[k * 32 + wv * 8];
            float4 xb = *(const float4*)&x_lds[k * 32 + wv * 8 + 4];
            float xs[8] = {xa.x, xa.y, xa.z, xa.w, xb.x, xb.y, xb.z, xb.w};
            float wvv[16] = {wq0.x, wq0.y, wq0.z, wq0.w, wq1.x, wq1.y, wq1.z, wq1.w,
                             wq2.x, wq2.y, wq2.z, wq2.w, wq3.x, wq3.y, wq3.z, wq3.w};
#pragma unroll
            for (int t = 0; t < 8; ++t) {
                float xv = xs[t];
#pragma unroll
                for (int j = 0; j < 16; ++j) acc[t][j] = fmaf(xv, wvv[j], acc[t][j]);
            }
        }
        __syncthreads();
    }
    float w2v[16];
#pragma unroll
    for (int m = 0; m < 4; ++m) {
        float4 v = *(const float4*)&w2[m * 256 + l * 4];
        w2v[m*4+0] = v.x; w2v[m*4+1] = v.y; w2v[m*4+2] = v.z; w2v[m*4+3] = v.w;
    }
    int* idx_sh = (int*)w_lds;
    float* red = (float*)(w_lds + 64);
#pragma unroll
    for (int t = 0; t < 8; ++t) {
        float bv = FLT_MAX; int bi = 0;
#pragma unroll
        for (int m = 0; m < 4; ++m)
#pragma unroll
            for (int j = 0; j < 4; ++j) {
                float s = w2v[m*4+j] - 2.f * acc[t][m*4+j];
                int c = m * 256 + l * 4 + j;
                if (s < bv) { bv = s; bi = c; }
            }
#pragma unroll
        for (int off = 32; off > 0; off >>= 1) {
            float ov = __shfl_xor(bv, off);
            int oi = __shfl_xor(bi, off);
            if (ov < bv || (ov == bv && oi < bi)) { bv = ov; bi = oi; }
        }
        if (l == 0) idx_sh[wv * 8 + t] = bi;
    }
    __syncthreads();
    if (tid < 32) atomicAdd(&hist[idx_sh[tid]], 1);
    float lsum = 0.f;
    for (int e = tid; e < C_DIM * 32; e += 256) {
        int t = e & 31, c = e >> 5;
        int id = idx_sh[t];
        float q = emb[(size_t)id * C_DIM + c];
        float xv = x_lds[c * 32 + t];
        float d = q - xv;
        lsum += d * d;
        out[((size_t)(b * C_DIM + c) << 10) + hw0 + t] = q;
    }
#pragma unroll
    for (int off = 32; off > 0; off >>= 1) lsum += __shfl_down(lsum, off);
    if (l == 0) red[wv] = lsum;
    __syncthreads();
    if (tid == 0) atomicAdd(lossp, red[0] + red[1] + red[2] + red[3]);
}

extern "C" void kernel_launch(void* const* d_in, const int* in_sizes, int n_in,
                              void* d_out, int out_size, void* d_ws, size_t ws_size,
                              hipStream_t stream) {
    const float* x   = (const float*)d_in[0];
    const float* emb = (const float*)d_in[1];
    float* out = (float*)d_out;
    char* ws = (char*)d_ws;
    int*   hist  = (int*)(ws + WS_HIST);
    float* lossp = (float*)(ws + WS_LOSS);
    float* w2    = (float*)(ws + WS_W2);
    int*   cntp  = (int*)(ws + WS_CNT);

    if (ws_size >= WS_NEED) {
        unsigned short* wpack = (unsigned short*)(ws + WS_WPK);
        split_w<<<1024, 64, 0, stream>>>(emb, wpack, w2, hist, lossp, cntp);
        vq_fused6<<<256, 512, 0, stream>>>(x, emb, wpack, w2, out, hist, lossp, cntp);
    } else {
        hipMemsetAsync(d_ws, 0, 4608, stream);
        w2_kernel<<<4, 256, 0, stream>>>(emb, w2);
        vq_main<<<1024, 256, 0, stream>>>(x, emb, out, hist, lossp, w2);
        finalize_kernel<<<1, 1024, 0, stream>>>(hist, lossp, out);
    }
}

// Round 11
// 146.614 us; speedup vs baseline: 1.2604x; 1.0498x over previous
//
#include <hip/hip_runtime.h>
#include <hip/hip_bf16.h>
#include <cfloat>
#include <math.h>

#define N_TOK   32768
#define S_CODES 1024
#define C_DIM   256

typedef __attribute__((ext_vector_type(8))) short short8v;
typedef __attribute__((ext_vector_type(4))) float float4v;

// ---- workspace byte offsets ----
#define WS_HIST 0                       // 1024 int
#define WS_LOSS 4096                    // 1 float
#define WS_W2   4608                    // 1024 float
#define WS_WPK  16384                   // w_packed [1024 codes][8 kc][hi 64B | lo 64B] = 1 MB
#define WS_NEED ((size_t)(WS_WPK + 1048576))

__device__ __forceinline__ unsigned short f2bf(float f) {
    __hip_bfloat16 h = __float2bfloat16(f);
    return __builtin_bit_cast(unsigned short, h);
}
__device__ __forceinline__ float bf2f(unsigned short u) {
    return __bfloat162float(__builtin_bit_cast(__hip_bfloat16, u));
}
__device__ __forceinline__ void gload16(const void* g, void* l) {
    __builtin_amdgcn_global_load_lds((const __attribute__((address_space(1))) void*)g,
                                     (__attribute__((address_space(3))) void*)l, 16, 0, 0);
}

// ---- split w into packed hi/lo rows + squared norms; also zero hist/loss ----
// regridded 128 blocks x 512 thr (was 1024x64): identical per-(c,l) math, each
// code c maps to one whole wave (wave = c%8) so the shuffle reduce is unchanged.
__global__ void split_w(const float* __restrict__ w, unsigned short* __restrict__ wpack,
                        float* __restrict__ w2, int* __restrict__ hist,
                        float* __restrict__ lossp) {
    int tid = threadIdx.x;
    int c = blockIdx.x * 8 + (tid >> 6), l = tid & 63;
    float4 v = ((const float4*)(w + (size_t)c * C_DIM))[l];   // k = l*4 .. +3
    float s = v.x*v.x + v.y*v.y + v.z*v.z + v.w*v.w;
    float vv[4] = {v.x, v.y, v.z, v.w};
    ushort4 h4, l4;
    unsigned short* hp = (unsigned short*)&h4;
    unsigned short* lp = (unsigned short*)&l4;
#pragma unroll
    for (int q = 0; q < 4; ++q) {
        hp[q] = f2bf(vv[q]);
        lp[q] = f2bf(vv[q] - bf2f(hp[q]));
    }
    size_t base = ((size_t)c * 8 + (l >> 3)) * 64;            // 64 shorts = 128 B per (c,kc)
    *(ushort4*)&wpack[base + (l & 7) * 4] = h4;               // hi half (bytes 0..63)
    *(ushort4*)&wpack[base + 32 + (l & 7) * 4] = l4;          // lo half (bytes 64..127)
#pragma unroll
    for (int off = 32; off > 0; off >>= 1) s += __shfl_down(s, off);
    if (l == 0) w2[c] = s;
    if (l == 32) hist[c] = 0;
    if (c == 0 && l == 33) *lossp = 0.f;
}

// ---- main (r5's verified 77us kernel, byte-identical hot path).
//      128-token blocks, 8 waves (th = wv&1 token-half, cq = wv>>1 code-quarter).
//      x converted once, DIRECTLY from coalesced global reads (no LDS bounce, no
//      barriers) into full-K LDS hi/lo (128 KB); first two W tiles' DMA issued
//      BEFORE phase 1 so it hides under the conversion. W staged via global_load_lds
//      16 KB tiles, double-buffered, counted vmcnt(2). ----
__global__ void __launch_bounds__(512, 2)
vq_fused6(const float* __restrict__ x, const float* __restrict__ emb,
          const unsigned short* __restrict__ wpack, const float* __restrict__ w2g,
          float* __restrict__ out, int* __restrict__ hist, float* __restrict__ lossp) {
    __shared__ __align__(16) char smem[163840];
    // layout: xh [128 tok][256 k] bf16 (64 KB) | xl (64 KB) | W dbuf 2x16 KB
    unsigned short* xh = (unsigned short*)smem;
    unsigned short* xl = (unsigned short*)(smem + 65536);
    char* wbuf = smem + 131072;               // two 16 KB tile buffers
    char* scr  = smem + 131072;               // phase-3 scratch overlay (32 KB)

    const int tid = threadIdx.x;
    const int l = tid & 63, wv = tid >> 6;
    const int quad = l >> 4, lr = l & 15;
    const int th = wv & 1, cq = wv >> 1;      // token half / code quarter
    const int t0 = blockIdx.x * 128;
    const int b = t0 >> 10, hw0 = t0 & 1023;
    const size_t xbase = ((size_t)b << 18) + hw0;

    const int drq = l >> 3;                   // DMA: row within 8-row group
    const int dch = (l & 7) ^ (drq & 7);      // source chunk (un-swizzle)
    const char* wpc = (const char*)wpack;

    // stage 16 KB tile g (strip g>>3, kc g&7) into wbuf[g&1]; 8 waves x 2 KB
    auto STAGE = [&](int g) {
        int sp = g >> 3, kcp = g & 7;
        char* dst = wbuf + (g & 1) * 16384 + wv * 2048;
#pragma unroll
        for (int u = 0; u < 2; ++u) {
            int code = sp * 128 + wv * 16 + u * 8 + drq;
            size_t src = ((size_t)code * 8 + kcp) * 128 + (size_t)dch * 16;
            gload16(wpc + src, dst + u * 1024);
        }
    };

    // W tiles 0,1 DMA in flight during all of phase 1
    STAGE(0);
    STAGE(1);

    // ---- phase 1: convert x, barrier-free (coalesced scalar loads) ----
    float x2p = 0.f;                          // partial |x|^2: token ct, k-quarter kq
    {
        const int ct = tid & 127, kq = tid >> 7;
        const float* gp0 = x + xbase + (size_t)(kq * 8) * 1024 + ct;
#pragma unroll 2
        for (int kc = 0; kc < 8; ++kc) {
            const float* gp = gp0 + (size_t)(kc * 32) * 1024;
            float v8[8];
#pragma unroll
            for (int j2 = 0; j2 < 8; ++j2) v8[j2] = gp[(size_t)j2 * 1024];
            short8v hv, lv;
#pragma unroll
            for (int j2 = 0; j2 < 8; ++j2) {
                float v = v8[j2];
                unsigned short h = f2bf(v);
                float hf = bf2f(h);
                unsigned short lo = f2bf(v - hf);
                hv[j2] = (short)h; lv[j2] = (short)lo;
                x2p = fmaf(v, v, x2p);
            }
            int pos = (kc * 4 + kq) ^ (ct & 31);          // XOR swizzle, 16B chunks
            *(short8v*)&xh[ct * 256 + pos * 8] = hv;
            *(short8v*)&xl[ct * 256 + pos * 8] = lv;
        }
    }
    __syncthreads();   // xh/xl ready; full drain also retires tile-0/1 DMA

    // ---- precomputed fragment offsets ----
    int aoffb[4], axor[4];
#pragma unroll
    for (int i = 0; i < 4; ++i) {
        int arow = th * 64 + i * 16 + lr;     // token row 0..127
        aoffb[i] = arow * 512;                // bytes (row = 256 shorts)
        axor[i] = arow & 31;
    }
    int boff_h[2], boff_l[2];
#pragma unroll
    for (int j = 0; j < 2; ++j) {
        int brow = cq * 32 + j * 16 + lr;     // row in 128-code tile, 128 B rows
        boff_h[j] = brow * 128 + ((quad ^ (brow & 7)) * 16);
        boff_l[j] = brow * 128 + (((4 + quad) ^ (brow & 7)) * 16);
    }

    float bval[16]; int bidx[16];
#pragma unroll
    for (int s2 = 0; s2 < 16; ++s2) { bval[s2] = FLT_MAX; bidx[s2] = 0; }
    const float4v zacc = {0.f, 0.f, 0.f, 0.f};
    float4v acc[4][2];
#pragma unroll
    for (int i = 0; i < 4; ++i)
#pragma unroll
        for (int j = 0; j < 2; ++j) acc[i][j] = zacc;

    struct Frags { short8v ah[4], al[4], bh[2], bl[2]; };
    Frags f0, f1;

    // read the 12 fragments for step g into f (A from immutable xh/xl, B from wbuf)
    auto READF = [&](Frags& f, int g) {
        const int kc = g & 7;
        const char* bufp = wbuf + (g & 1) * 16384;
#pragma unroll
        for (int i = 0; i < 4; ++i) {
            int pos = ((kc * 4 + quad) ^ axor[i]) * 16;
            f.ah[i] = *(const short8v*)(smem + aoffb[i] + pos);
            f.al[i] = *(const short8v*)(smem + 65536 + aoffb[i] + pos);
        }
#pragma unroll
        for (int j = 0; j < 2; ++j) {
            f.bh[j] = *(const short8v*)(bufp + boff_h[j]);
            f.bl[j] = *(const short8v*)(bufp + boff_l[j]);
        }
    };

    auto COMPUTE = [&](const Frags& f) {
        __builtin_amdgcn_s_setprio(1);
#pragma unroll
        for (int i = 0; i < 4; ++i)
#pragma unroll
            for (int j = 0; j < 2; ++j) {
                acc[i][j] = __builtin_amdgcn_mfma_f32_16x16x32_bf16(f.ah[i], f.bh[j], acc[i][j], 0, 0, 0);
                acc[i][j] = __builtin_amdgcn_mfma_f32_16x16x32_bf16(f.ah[i], f.bl[j], acc[i][j], 0, 0, 0);
                acc[i][j] = __builtin_amdgcn_mfma_f32_16x16x32_bf16(f.al[i], f.bh[j], acc[i][j], 0, 0, 0);
            }
        __builtin_amdgcn_s_setprio(0);
    };

    // fold strip s into running argmin, then reset acc (w2 global loads enter the
    // vmcnt FIFO; the next counted wait retires them along with the older DMAs)
    auto FOLD = [&](int s) {
#pragma unroll
        for (int j = 0; j < 2; ++j) {
            int code = s * 128 + cq * 32 + j * 16 + lr;
            float w2c = w2g[code];
#pragma unroll
            for (int i = 0; i < 4; ++i) {
#pragma unroll
                for (int rr = 0; rr < 4; ++rr) {
                    float sv = fmaf(-2.f, acc[i][j][rr], w2c);
                    int slot = i * 4 + rr;
                    if (sv < bval[slot]) { bval[slot] = sv; bidx[slot] = code; }
                }
                acc[i][j] = zacc;
            }
        }
    };

#define SBAR0() __builtin_amdgcn_sched_barrier(0)

    // ---- phase 2: 64 steps, frag-pipelined (read g+1 while computing g) ----
    READF(f0, 0);

#pragma unroll 1
    for (int t = 0; t < 31; ++t) {
        const int g = 2 * t;
        // ---- body g: prefetch f1 <- g+1, compute f0, DMA tile g+2 ----
        asm volatile("s_barrier" ::: "memory");        // frags g read by all -> buf[g&1] free
        STAGE(g + 2);
        asm volatile("s_waitcnt vmcnt(2)\n\ts_barrier" ::: "memory");  // tile g+1 ready (all waves)
        READF(f1, g + 1);
        SBAR0();                                       // pin: MFMA may not hoist above
        COMPUTE(f0);
        SBAR0();
        // ---- body g+1: prefetch f0 <- g+2, compute f1, DMA tile g+3 ----
        asm volatile("s_barrier" ::: "memory");
        STAGE(g + 3);
        asm volatile("s_waitcnt vmcnt(2)\n\ts_barrier" ::: "memory");
        READF(f0, g + 2);
        SBAR0();
        COMPUTE(f1);
        SBAR0();
        if ((t & 3) == 3) FOLD((2 * t + 1) >> 3);      // strip fold at g = 7,15,..,55
    }
    // ---- body 62: compute f0 (frags 62), prefetch f1 <- 63 ----
    asm volatile("s_barrier" ::: "memory");            // frags 62 read -> safe
    asm volatile("s_waitcnt vmcnt(0)\n\ts_barrier" ::: "memory");      // tile 63 ready
    READF(f1, 63);
    SBAR0();
    COMPUTE(f0);
    SBAR0();
    // ---- body 63: compute f1, final fold ----
    COMPUTE(f1);
    FOLD(7);

    // ---- phase 3: x2 reduce, argmin reduce, histogram, loss, gather/write ----
    __syncthreads();                          // all DMA + reads done; scr free
    float* bestv = (float*)scr;               // [8][64]
    int*   besti = (int*)(scr + 2048);        // [8][64]
    int*   idx_sh = (int*)(scr + 4096);       // [128]
    float* x2sh  = (float*)(scr + 8192);      // [4][128]
    x2sh[tid] = x2p;                          // tid = kq*128 + ct
#pragma unroll
    for (int slot = 0; slot < 16; ++slot) {
        float bv = bval[slot]; int bi = bidx[slot];
#pragma unroll
        for (int off = 1; off < 16; off <<= 1) {
            float ov = __shfl_xor(bv, off);
            int   oi = __shfl_xor(bi, off);
            if (ov < bv || (ov == bv && oi < bi)) { bv = ov; bi = oi; }
        }
        if (lr == 0) {
            int tloc = (slot >> 2) * 16 + quad * 4 + (slot & 3);   // 0..63 within half
            bestv[wv * 64 + tloc] = bv; besti[wv * 64 + tloc] = bi;
        }
    }
    __syncthreads();
    if (tid < 128) {
        float x2tok = x2sh[tid] + x2sh[128 + tid] + x2sh[256 + tid] + x2sh[384 + tid];
        int th2 = tid >> 6, tl = tid & 63;    // waves with th==th2: {th2, th2+2, th2+4, th2+6}
        float bv = bestv[th2 * 64 + tl]; int bi = besti[th2 * 64 + tl];
#pragma unroll
        for (int w = 1; w < 4; ++w) {
            float ov = bestv[(w * 2 + th2) * 64 + tl];
            int   oi = besti[(w * 2 + th2) * 64 + tl];
            if (ov < bv || (ov == bv && oi < bi)) { bv = ov; bi = oi; }
        }
        idx_sh[tid] = bi;
        atomicAdd(&hist[bi], 1);
        float lsum = bv + x2tok;              // |q-x|^2 = (w2 - 2 q.x) + x^2
#pragma unroll
        for (int off = 32; off > 0; off >>= 1) lsum += __shfl_down(lsum, off);
        if ((tid & 63) == 0) atomicAdd(lossp, lsum);
    }
    __syncthreads();
    {
        int t = tid & 127, cg = tid >> 7;
        int id = idx_sh[t];
        const float* erow = emb + (size_t)id * C_DIM;
        float* ob = out + xbase + t;
#pragma unroll
        for (int cb = 0; cb < 16; ++cb) {
            int c4 = cb * 16 + cg * 4;
            float4 q4 = *(const float4*)&erow[c4];
            ob[(size_t)(c4 + 0) * 1024] = q4.x;
            ob[(size_t)(c4 + 1) * 1024] = q4.y;
            ob[(size_t)(c4 + 2) * 1024] = q4.z;
            ob[(size_t)(c4 + 3) * 1024] = q4.w;
        }
    }
#undef SBAR0
}

__global__ void finalize_kernel(const int* __restrict__ hist, const float* __restrict__ lossp,
                                float* __restrict__ out) {
    __shared__ float red[16];
    int tid = threadIdx.x;                  // 1024 threads
    float p = (float)hist[tid] * (1.f / 32768.f);
    float term = p * logf(p + 1e-6f);
#pragma unroll
    for (int off = 32; off > 0; off >>= 1) term += __shfl_down(term, off);
    if ((tid & 63) == 0) red[tid >> 6] = term;
    __syncthreads();
    if (tid == 0) {
        float s = 0.f;
#pragma unroll
        for (int i = 0; i < 16; ++i) s += red[i];
        out[8388608] = 0.25f * lossp[0] * (1.f / 8388608.f);   // quant_loss
        out[8388609] = expf(-s);                               // perplexity
    }
}

// ---- fallback path (round-1 kernel, known-correct) used only if ws too small ----
__global__ void w2_kernel(const float* __restrict__ w, float* __restrict__ w2) {
    int code = blockIdx.x * blockDim.x + threadIdx.x;
    const float4* r = (const float4*)(w + (size_t)code * C_DIM);
    float s = 0.f;
#pragma unroll 8
    for (int i = 0; i < C_DIM / 4; ++i) {
        float4 v = r[i];
        s += v.x * v.x + v.y * v.y + v.z * v.z + v.w * v.w;
    }
    w2[code] = s;
}

__launch_bounds__(256, 2)
__global__ void vq_main(const float* __restrict__ x, const float* __restrict__ emb,
                        float* __restrict__ out, int* __restrict__ hist,
                        float* __restrict__ lossp, const float* __restrict__ w2) {
    __shared__ float w_lds[8 * S_CODES];
    __shared__ float x_lds[C_DIM * 32];
    const int tid = threadIdx.x;
    const int l = tid & 63, wv = tid >> 6;
    const int t0 = blockIdx.x * 32;
    const int b = t0 >> 10, hw0 = t0 & 1023;
    const float* xbase = x + ((size_t)b * C_DIM << 10) + hw0;
    {
        int rl = tid & 7, r0 = tid >> 3;
        for (int rep = 0; rep < 8; ++rep) {
            int c = rep * 32 + r0;
            float4 v = *(const float4*)(xbase + ((size_t)c << 10) + rl * 4);
            *(float4*)&x_lds[c * 32 + rl * 4] = v;
        }
    }
    float4 pre[8];
#pragma unroll
    for (int m = 0; m < 8; ++m) {
        int fid = m * 256 + tid;
        int code = fid >> 1, kq = fid & 1;
        pre[m] = *(const float4*)(emb + (size_t)code * C_DIM + kq * 4);
    }
    float acc[8][16];
#pragma unroll
    for (int t = 0; t < 8; ++t)
#pragma unroll
        for (int j = 0; j < 16; ++j) acc[t][j] = 0.f;
    __syncthreads();
    for (int chunk = 0; chunk < 32; ++chunk) {
#pragma unroll
        for (int m = 0; m < 8; ++m) {
            int fid = m * 256 + tid;
            int code = fid >> 1, kq = fid & 1;
            float4 v = pre[m];
            w_lds[(kq * 4 + 0) * S_CODES + code] = v.x;
            w_lds[(kq * 4 + 1) * S_CODES + code] = v.y;
            w_lds[(kq * 4 + 2) * S_CODES + code] = v.z;
            w_lds[(kq * 4 + 3) * S_CODES + code] = v.w;
        }
        if (chunk + 1 < 32) {
            int k0n = (chunk + 1) * 8;
#pragma unroll
            for (int m = 0; m < 8; ++m) {
                int fid = m * 256 + tid;
                int code = fid >> 1, kq = fid & 1;
                pre[m] = *(const float4*)(emb + (size_t)code * C_DIM + k0n + kq * 4);
            }
        }
        __syncthreads();
        int k0 = chunk * 8;
#pragma unroll
        for (int kk = 0; kk < 8; ++kk) {
            int k = k0 + kk;
            float4 wq0 = *(const float4*)&w_lds[kk * S_CODES +   0 + l * 4];
            float4 wq1 = *(const float4*)&w_lds[kk * S_CODES + 256 + l * 4];
            float4 wq2 = *(const float4*)&w_lds[kk * S_CODES + 512 + l * 4];
            float4 wq3 = *(const float4*)&w_lds[kk * S_CODES + 768 + l * 4];
            float4 xa = *(const float4*)&x_lds[k * 32 + wv * 8];
            float4 xb = *(const float4*)&x_lds[k * 32 + wv * 8 + 4];
            float xs[8] = {xa.x, xa.y, xa.z, xa.w, xb.x, xb.y, xb.z, xb.w};
            float wvv[16] = {wq0.x, wq0.y, wq0.z, wq0.w, wq1.x, wq1.y, wq1.z, wq1.w,
                             wq2.x, wq2.y, wq2.z, wq2.w, wq3.x, wq3.y, wq3.z, wq3.w};
#pragma unroll
            for (int t = 0; t < 8; ++t) {
                float xv = xs[t];
#pragma unroll
                for (int j = 0; j < 16; ++j) acc[t][j] = fmaf(xv, wvv[j], acc[t][j]);
            }
        }
        __syncthreads();
    }
    float w2v[16];
#pragma unroll
    for (int m = 0; m < 4; ++m) {
        float4 v = *(const float4*)&w2[m * 256 + l * 4];
        w2v[m*4+0] = v.x; w2v[m*4+1] = v.y; w2v[m*4+2] = v.z; w2v[m*4+3] = v.w;
    }
    int* idx_sh = (int*)w_lds;
    float* red = (float*)(w_lds + 64);
#pragma unroll
    for (int t = 0; t < 8; ++t) {
        float bv = FLT_MAX; int bi = 0;
#pragma unroll
        for (int m = 0; m < 4; ++m)
#pragma unroll
            for (int j = 0; j < 4; ++j) {
                float s = w2v[m*4+j] - 2.f * acc[t][m*4+j];
                int c = m * 256 + l * 4 + j;
                if (s < bv) { bv = s; bi = c; }
            }
#pragma unroll
        for (int off = 32; off > 0; off >>= 1) {
            float ov = __shfl_xor(bv, off);
            int oi = __shfl_xor(bi, off);
            if (ov < bv || (ov == bv && oi < bi)) { bv = ov; bi = oi; }
        }
        if (l == 0) idx_sh[wv * 8 + t] = bi;
    }
    __syncthreads();
    if (tid < 32) atomicAdd(&hist[idx_sh[tid]], 1);
    float lsum = 0.f;
    for (int e = tid; e < C_DIM * 32; e += 256) {
        int t = e & 31, c = e >> 5;
        int id = idx_sh[t];
        float q = emb[(size_t)id * C_DIM + c];
        float xv = x_lds[c * 32 + t];
        float d = q - xv;
        lsum += d * d;
        out[((size_t)(b * C_DIM + c) << 10) + hw0 + t] = q;
    }
#pragma unroll
    for (int off = 32; off > 0; off >>= 1) lsum += __shfl_down(lsum, off);
    if (l == 0) red[wv] = lsum;
    __syncthreads();
    if (tid == 0) atomicAdd(lossp, red[0] + red[1] + red[2] + red[3]);
}

extern "C" void kernel_launch(void* const* d_in, const int* in_sizes, int n_in,
                              void* d_out, int out_size, void* d_ws, size_t ws_size,
                              hipStream_t stream) {
    const float* x   = (const float*)d_in[0];
    const float* emb = (const float*)d_in[1];
    float* out = (float*)d_out;
    char* ws = (char*)d_ws;
    int*   hist  = (int*)(ws + WS_HIST);
    float* lossp = (float*)(ws + WS_LOSS);
    float* w2    = (float*)(ws + WS_W2);

    if (ws_size >= WS_NEED) {
        unsigned short* wpack = (unsigned short*)(ws + WS_WPK);
        split_w<<<128, 512, 0, stream>>>(emb, wpack, w2, hist, lossp);
        vq_fused6<<<256, 512, 0, stream>>>(x, emb, wpack, w2, out, hist, lossp);
    } else {
        hipMemsetAsync(d_ws, 0, 4608, stream);
        w2_kernel<<<4, 256, 0, stream>>>(emb, w2);
        vq_main<<<1024, 256, 0, stream>>>(x, emb, out, hist, lossp, w2);
    }
    finalize_kernel<<<1, 1024, 0, stream>>>(hist, lossp, out);
}